// Round 4
// baseline (701.853 us; speedup 1.0000x reference)
//
#include <hip/hip_runtime.h>
#include <hip/hip_bf16.h>

// Problem constants (static, shape-derived)
#define S 8192
#define E 64
#define CAP 160            // floor(1.25*8192/64)=160, even, >=4
#define EC (E * CAP)       // 10240 floats per token slab
#define OUT_HALF ((size_t)S * EC)        // 83,886,080 elements per output tensor
#define TOT_F4 (2 * OUT_HALF / 4)        // 41,943,040 f32x4 in d_out

typedef float f32x4 __attribute__((ext_vector_type(4)));

// ---------------------------------------------------------------------------
// Kernel 0: bulk zero of the whole output. Mirrors the rocclr fillBuffer
// pattern that measures 6.27 TB/s on this chip: grid-stride, plain
// dwordx4 stores, no per-element branching.
// ---------------------------------------------------------------------------
__global__ __launch_bounds__(256) void zero_kernel(float* __restrict__ out) {
  f32x4* o = (f32x4*)out;
  size_t i = (size_t)blockIdx.x * 256 + threadIdx.x;
  size_t stride = (size_t)gridDim.x * 256;
  f32x4 z = {0.f, 0.f, 0.f, 0.f};
  for (; i < TOT_F4; i += stride) o[i] = z;
}

// ---------------------------------------------------------------------------
// Kernel 1: per-token argmax (first-index tiebreak) + softmax gate value.
// One wave (64 lanes) per token; 64 experts -> one element per lane.
// ---------------------------------------------------------------------------
__global__ __launch_bounds__(256) void router_kernel(
    const float* __restrict__ x, int* __restrict__ eidx, float* __restrict__ gate) {
  const int wavesPerBlock = 4;
  int token = blockIdx.x * wavesPerBlock + (threadIdx.x >> 6);
  int lane = threadIdx.x & 63;
  if (token >= S) return;

  float v = x[(size_t)token * E + lane];

  // argmax reduction, lowest index wins ties (jnp.argmax semantics)
  float mval = v;
  int midx = lane;
  #pragma unroll
  for (int off = 32; off; off >>= 1) {
    float ov = __shfl_xor(mval, off);
    int oi = __shfl_xor(midx, off);
    if (ov > mval || (ov == mval && oi < midx)) { mval = ov; midx = oi; }
  }

  // softmax denominator with max subtraction
  float ev = __expf(v - mval);
  float sum = ev;
  #pragma unroll
  for (int off = 32; off; off >>= 1) sum += __shfl_xor(sum, off);

  if (lane == 0) {
    eidx[token] = midx;
    gate[token] = 1.0f / sum;   // softmax value at the argmax position
  }
}

// ---------------------------------------------------------------------------
// Kernel 2: per-expert exclusive cumsum rank in token order, with the
// surviving (weight, 1.0) pairs scattered directly into the zeroed output.
// 64 blocks (one per expert) x 256 threads; ballot/popcount chunk scan.
// Total scattered stores: <= 2*8192 — noise next to the 671 MB zero fill.
// ---------------------------------------------------------------------------
__global__ __launch_bounds__(256) void rank_scatter_kernel(
    const int* __restrict__ eidx, const float* __restrict__ gate,
    float* __restrict__ out) {
  int expert = blockIdx.x;
  int tid = threadIdx.x;
  int lane = tid & 63;
  int wid = tid >> 6;

  __shared__ int warp_tot[4];
  int running = 0;

  for (int base = 0; base < S; base += 256) {
    int t = base + tid;
    bool match = (eidx[t] == expert);
    unsigned long long bal = __ballot(match);
    int lanePre = __popcll(bal & ((1ull << lane) - 1ull));
    int waveTot = __popcll(bal);
    if (lane == 0) warp_tot[wid] = waveTot;
    __syncthreads();
    int wbase = 0;
    #pragma unroll
    for (int w = 0; w < 4; ++w) if (w < wid) wbase += warp_tot[w];
    int blockTot = warp_tot[0] + warp_tot[1] + warp_tot[2] + warp_tot[3];
    int r = running + wbase + lanePre;
    if (match && r < CAP) {
      size_t off = (size_t)t * EC + expert * CAP + r;
      out[off] = gate[t];
      out[OUT_HALF + off] = 1.0f;
    }
    running += blockTot;
    __syncthreads();                 // protect warp_tot before next iteration
  }
}

extern "C" void kernel_launch(void* const* d_in, const int* in_sizes, int n_in,
                              void* d_out, int out_size, void* d_ws, size_t ws_size,
                              hipStream_t stream) {
  const float* x = (const float*)d_in[0];
  float* out = (float*)d_out;

  // workspace: eidx[S] int, gate[S] float  (64 KB)
  int* eidx = (int*)d_ws;
  float* gate = (float*)((char*)d_ws + S * sizeof(int));

  zero_kernel<<<2048, 256, 0, stream>>>(out);
  router_kernel<<<S / 4, 256, 0, stream>>>(x, eidx, gate);
  rank_scatter_kernel<<<E, 256, 0, stream>>>(eidx, gate, out);
}

// Round 5
// 663.936 us; speedup vs baseline: 1.0571x; 1.0571x over previous
//
#include <hip/hip_runtime.h>
#include <hip/hip_bf16.h>

// Problem constants (static, shape-derived)
#define S 8192
#define E 64
#define CAP 160            // floor(1.25*8192/64)=160, even, >=4
#define EC (E * CAP)       // 10240 floats per token slab
#define OUT_HALF ((size_t)S * EC)  // 83,886,080 elements per output tensor

// clang-native 16B vector: __builtin_nontemporal_store requires a native
// vector type, not HIP's float4 class.
typedef float f32x4 __attribute__((ext_vector_type(4)));

// ---------------------------------------------------------------------------
// Kernel 1: per-token argmax (first-index tiebreak) + softmax gate value.
// One wave (64 lanes) per token; 64 experts -> one element per lane.
// ---------------------------------------------------------------------------
__global__ __launch_bounds__(256) void router_kernel(
    const float* __restrict__ x, int* __restrict__ eidx, float* __restrict__ gate) {
  const int wavesPerBlock = 4;
  int token = blockIdx.x * wavesPerBlock + (threadIdx.x >> 6);
  int lane = threadIdx.x & 63;
  if (token >= S) return;

  float v = x[(size_t)token * E + lane];

  // argmax reduction, lowest index wins ties (jnp.argmax semantics)
  float mval = v;
  int midx = lane;
  #pragma unroll
  for (int off = 32; off; off >>= 1) {
    float ov = __shfl_xor(mval, off);
    int oi = __shfl_xor(midx, off);
    if (ov > mval || (ov == mval && oi < midx)) { mval = ov; midx = oi; }
  }

  // softmax denominator with max subtraction
  float ev = __expf(v - mval);
  float sum = ev;
  #pragma unroll
  for (int off = 32; off; off >>= 1) sum += __shfl_xor(sum, off);

  if (lane == 0) {
    eidx[token] = midx;
    gate[token] = 1.0f / sum;   // softmax value at the argmax position
  }
}

// ---------------------------------------------------------------------------
// Kernel 2: per-expert exclusive cumsum rank in token order.
// 64 blocks (one per expert) x 256 threads; ballot/popcount chunk scan.
// ---------------------------------------------------------------------------
__global__ __launch_bounds__(256) void rank_kernel(
    const int* __restrict__ eidx, int* __restrict__ rank) {
  int expert = blockIdx.x;
  int tid = threadIdx.x;
  int lane = tid & 63;
  int wid = tid >> 6;

  __shared__ int warp_tot[4];
  int running = 0;

  for (int base = 0; base < S; base += 256) {
    int t = base + tid;
    bool match = (eidx[t] == expert);
    unsigned long long bal = __ballot(match);
    int lanePre = __popcll(bal & ((1ull << lane) - 1ull));
    int waveTot = __popcll(bal);
    if (lane == 0) warp_tot[wid] = waveTot;
    __syncthreads();
    int wbase = 0;
    #pragma unroll
    for (int w = 0; w < 4; ++w) if (w < wid) wbase += warp_tot[w];
    int blockTot = warp_tot[0] + warp_tot[1] + warp_tot[2] + warp_tot[3];
    if (match) rank[t] = running + wbase + lanePre;
    running += blockTot;
    __syncthreads();                 // protect warp_tot before next iteration
  }
}

// ---------------------------------------------------------------------------
// Kernel 3: single-pass zero+place of the full dense output. One block per
// token; per-component compares compile to v_cndmask in registers, stores
// are nontemporal dwordx4 (no point caching a pure store stream).
// Measured best structure: fused fill beats zero_kernel+scatter by ~37 µs
// (scatter RMWs dirty lines; extra launch).
// ---------------------------------------------------------------------------
__global__ __launch_bounds__(256) void fill_kernel(
    const int* __restrict__ eidx, const float* __restrict__ gate,
    const int* __restrict__ rank, float* __restrict__ out) {
  int token = blockIdx.x;
  int tid = threadIdx.x;

  int ex = eidx[token];
  int rk = rank[token];
  float w = gate[token];
  int p = (rk < CAP) ? (ex * CAP + rk) : -1;  // flat slab position, -1 = dropped

  f32x4* cw = (f32x4*)(out + (size_t)token * EC);
  f32x4* sm = (f32x4*)(out + OUT_HALF + (size_t)token * EC);

  #pragma unroll
  for (int j = 0; j < EC / 4 / 256; ++j) {    // 2560 float4 / 256 threads = 10
    int f4 = j * 256 + tid;
    int base4 = f4 * 4;
    f32x4 v;
    v.x = (p == base4 + 0) ? w : 0.f;
    v.y = (p == base4 + 1) ? w : 0.f;
    v.z = (p == base4 + 2) ? w : 0.f;
    v.w = (p == base4 + 3) ? w : 0.f;
    f32x4 m;
    m.x = (p == base4 + 0) ? 1.f : 0.f;
    m.y = (p == base4 + 1) ? 1.f : 0.f;
    m.z = (p == base4 + 2) ? 1.f : 0.f;
    m.w = (p == base4 + 3) ? 1.f : 0.f;
    __builtin_nontemporal_store(v, &cw[f4]);
    __builtin_nontemporal_store(m, &sm[f4]);
  }
}

extern "C" void kernel_launch(void* const* d_in, const int* in_sizes, int n_in,
                              void* d_out, int out_size, void* d_ws, size_t ws_size,
                              hipStream_t stream) {
  const float* x = (const float*)d_in[0];
  float* out = (float*)d_out;

  // workspace: eidx[S] int, gate[S] float, rank[S] int  (96 KB total)
  int* eidx = (int*)d_ws;
  float* gate = (float*)((char*)d_ws + S * sizeof(int));
  int* rank = (int*)((char*)d_ws + 2 * S * sizeof(int));

  router_kernel<<<S / 4, 256, 0, stream>>>(x, eidx, gate);
  rank_kernel<<<E, 256, 0, stream>>>(eidx, rank);
  fill_kernel<<<S, 256, 0, stream>>>(eidx, gate, rank, out);
}